// Round 8
// baseline (353.409 us; speedup 1.0000x reference)
//
#include <hip/hip_runtime.h>
#include <hip/hip_bf16.h>

#define BATCH 32
#define DIM   128
#define NPTS  2048
#define NCH   16          // 16-byte chunks (8 bf16) per point
#define BIGF  1e30f
#define DGRID 1024        // dist grid: 4 jq x 8 it x 32 b

// ws byte offsets; images are CHUNK-MAJOR: img[b][c][n] in 16B units
#define OFF_XT   0ull
#define OFF_YT   16777216ull
#define OFF_XN   33554432ull
#define OFF_YN   (OFF_XN + 262144ull)
#define OFF_RMIN (OFF_XN + 2ull * 262144ull)   // uint-ordered nonneg floats
#define OFF_CMIN (OFF_XN + 3ull * 262144ull)   // uint-ordered nonneg floats
#define OFF_LEN  (OFF_XN + 4ull * 262144ull)   // 32 ints
#define OFF_CTR  (OFF_LEN + 128ull)            // completion counter

typedef __bf16 bf16x8 __attribute__((ext_vector_type(8)));
typedef float  f32x16 __attribute__((ext_vector_type(16)));
typedef unsigned int u32;

#define ZERO16 {0.f,0.f,0.f,0.f,0.f,0.f,0.f,0.f,0.f,0.f,0.f,0.f,0.f,0.f,0.f,0.f}

__device__ __forceinline__ bool mask_is_i32(const void* m) {
  // mask[0][1] is guaranteed true (lens >= N/2 > 1); for int32 its byte 1 is 0.
  return ((const unsigned char*)m)[1] == 0;
}
__device__ __forceinline__ bool mask_at(const void* m, bool i32, int idx) {
  return i32 ? (((const int*)m)[idx] != 0) : (((const unsigned char*)m)[idx] != 0);
}

// async 16B global -> LDS (dst must be wave-linear: base + lane*16)
__device__ __forceinline__ void gll16(const void* g, void* l) {
  __builtin_amdgcn_global_load_lds(
      (const __attribute__((address_space(1))) u32*)g,
      (__attribute__((address_space(3))) u32*)l, 16, 0, 0);
}

// -------- kernel 1: transpose -> chunk-major bf16 image + norms + lens + init ----
// grid: 2 arr x 32 b x 32 nt = 2048 blocks, 256 threads; tile 128 d x 64 n
__global__ void chamfer_prep(const float* __restrict__ x, const float* __restrict__ y,
                             const void* __restrict__ mask, char* __restrict__ ws) {
  __shared__ float buf[128 * 65];       // [d][n], pitch 65 words -> 2-way banks
  __shared__ float nrm_part[4][64];
  __shared__ int pc[4];

  int blk = blockIdx.x;
  int arr = blk >> 10;
  int b   = (blk >> 5) & 31;
  int nt  = blk & 31;
  int n0  = nt << 6;                    // 64 points per block
  int tid = threadIdx.x;
  bool i32m = mask_is_i32(mask);

  if (blk == 0 && tid == 0) *(int*)(ws + OFF_CTR) = 0;

  // lens: popcount of mask row (one block per b does it)
  if (arr == 0 && nt == 0) {
    int cnt = 0;
#pragma unroll
    for (int k = 0; k < 8; ++k)
      cnt += mask_at(mask, i32m, b * NPTS + k * 256 + tid) ? 1 : 0;
#pragma unroll
    for (int s = 1; s < 64; s <<= 1) cnt += __shfl_xor(cnt, s);
    if ((tid & 63) == 0) pc[tid >> 6] = cnt;
    __syncthreads();
    if (tid == 0)
      ((int*)(ws + OFF_LEN))[b] = pc[0] + pc[1] + pc[2] + pc[3];
  }

  float* nrm  = (float*)(ws + (arr ? OFF_YN : OFF_XN));
  unsigned* minarr = (unsigned*)(ws + (arr ? OFF_CMIN : OFF_RMIN));

  // prefix mask: tile fully invalid iff its first point is invalid
  if (!mask_at(mask, i32m, b * NPTS + n0)) {
    if (tid < 64) {
      nrm[b * NPTS + n0 + tid] = BIGF;
      minarr[b * NPTS + n0 + tid] = __float_as_uint(BIGF);
    }
    return;
  }

  const float* src = (arr ? y : x) + (size_t)b * DIM * NPTS;
#pragma unroll
  for (int k = 0; k < 8; ++k) {
    int idx = k * 256 + tid;            // 128 d x 16 float4-cols
    int d = idx >> 4, c4 = idx & 15;
    *(float4*)&buf[d * 65 + c4 * 4] =
        *(const float4*)(src + (size_t)d * NPTS + n0 + c4 * 4);
  }
  __syncthreads();

  int n = tid & 63, grp = tid >> 6;     // grp: 32 dims each
  char* imgbase = ws + (arr ? OFF_YT : OFF_XT);
  float sq = 0.f;
#pragma unroll
  for (int cl = 0; cl < 4; ++cl) {
    unsigned short h[8];
#pragma unroll
    for (int q = 0; q < 8; ++q) {
      float v = buf[(grp * 32 + cl * 8 + q) * 65 + n];
      __hip_bfloat16 bv = __float2bfloat16(v);
      h[q] = *(unsigned short*)&bv;
      float vb = __bfloat162float(bv);
      sq = fmaf(vb, vb, sq);            // norm from ROUNDED value (matches MFMA)
    }
    uint4 pk;
    pk.x = h[0] | ((unsigned)h[1] << 16);
    pk.y = h[2] | ((unsigned)h[3] << 16);
    pk.z = h[4] | ((unsigned)h[5] << 16);
    pk.w = h[6] | ((unsigned)h[7] << 16);
    int cg = grp * 4 + cl;
    // chunk-major: consecutive n lanes -> contiguous 1KB writes
    *(uint4*)(imgbase + (((size_t)(b * NCH + cg) * NPTS + n0 + n) << 4)) = pk;
  }
  nrm_part[grp][n] = sq;
  __syncthreads();
  if (grp == 0) {
    float tot = nrm_part[0][n] + nrm_part[1][n] + nrm_part[2][n] + nrm_part[3][n];
    int row = n0 + n;
    bool valid = mask_at(mask, i32m, b * NPTS + row);
    nrm[b * NPTS + row] = valid ? tot : BIGF;
    minarr[b * NPTS + row] = __float_as_uint(BIGF);
  }
}

// -------- kernel 2: MFMA distance + mins + fused final reduce ----------------
// grid DGRID blocks: blk -> b (fastest), it (256-row tile), jq (512-col chunk)
__global__ __launch_bounds__(512, 2)
void chamfer_dist(char* __restrict__ ws, const void* __restrict__ mask,
                  float* __restrict__ out) {
  __shared__ __align__(16) char ysl[2][NCH * 128 * 16];  // 2 x 32 KB
  __shared__ unsigned colmin_lds[512];
  __shared__ unsigned rowmin_lds[256];
  __shared__ float redbuf[512];
  __shared__ int sh_done;

  int blk = blockIdx.x;
  int b  = blk & 31;
  int it = (blk >> 5) & 7;
  int jq = blk >> 8;
  int i0 = it << 8;                     // 256-row tile
  int j0q = jq << 9;                    // 512-col chunk
  int tid = threadIdx.x, lane = tid & 63, w = tid >> 6;
  int qrow = w >> 1, qcol = w & 1;      // wave: 64 rows x 64 cols
  int la31 = lane & 31, la5 = lane >> 5;
  bool i32m = mask_is_i32(mask);

  int len = ((const int*)(ws + OFF_LEN))[b];
  bool active = (i0 < len) && (j0q < len);

  if (active) {
    const char* xTb = ws + OFF_XT + ((size_t)b * NCH * NPTS << 4);
    const char* yTb = ws + OFF_YT + ((size_t)b * NCH * NPTS << 4);
    const float* xng = (const float*)(ws + OFF_XN) + b * NPTS;
    const float* yng = (const float*)(ws + OFF_YN) + b * NPTS;
    unsigned* rowming = (unsigned*)(ws + OFF_RMIN) + b * NPTS;
    unsigned* colming = (unsigned*)(ws + OFF_CMIN) + b * NPTS;

    if (tid < 512) colmin_lds[tid] = __float_as_uint(BIGF);
    if (tid < 256) rowmin_lds[tid] = __float_as_uint(BIGF);

    int njt = (len - j0q + 127) >> 7; if (njt > 4) njt = 4;

    // A fragments -> registers (coalesced chunk-major reads, reused all jt)
    int r0 = i0 + qrow * 64 + la31;
    bf16x8 Areg0[8], Areg1[8];
#pragma unroll
    for (int kc = 0; kc < 8; ++kc) {
      int c = kc * 2 + la5;
      Areg0[kc] = *(const bf16x8*)(xTb + (((size_t)c * NPTS + r0) << 4));
      Areg1[kc] = *(const bf16x8*)(xTb + (((size_t)c * NPTS + r0 + 32) << 4));
    }

    // xn for this wave's rows (C/D layout: row=(r&3)+8*(r>>2)+4*la5)
    float xnr[2][16], rmin[2][16];
#pragma unroll
    for (int fm = 0; fm < 2; ++fm)
#pragma unroll
      for (int r = 0; r < 16; ++r) {
        int row = qrow * 64 + fm * 32 + (r & 3) + ((r >> 2) << 3) + (la5 << 2);
        xnr[fm][r] = xng[i0 + row];
        rmin[fm][r] = BIGF;             // min_j(yn_j - 2*dot); xn added at end
      }

    // stage jt 0 (async global->LDS, wave-linear dst)
#pragma unroll
    for (int k = 0; k < 4; ++k) {
      int idx = k * 512 + tid;          // c = idx>>7, jl = idx&127
      gll16(yTb + (((size_t)(idx >> 7) * NPTS + j0q + (idx & 127)) << 4),
            ysl[0] + idx * 16);
    }
    __syncthreads();

    int cur = 0;
    for (int jt = 0; jt < njt; ++jt) {
      if (jt + 1 < njt) {               // prefetch next tile before compute
        int j0n = j0q + ((jt + 1) << 7);
#pragma unroll
        for (int k = 0; k < 4; ++k) {
          int idx = k * 512 + tid;
          gll16(yTb + (((size_t)(idx >> 7) * NPTS + j0n + (idx & 127)) << 4),
                ysl[cur ^ 1] + idx * 16);
        }
      }
      int jloc = (jt << 7) + qcol * 64;       // within-chunk col base
      float ynr0 = yng[j0q + jloc + la31];
      float ynr1 = yng[j0q + jloc + 32 + la31];

      const char* ybuf = ysl[cur];
      f32x16 acc00 = ZERO16, acc01 = ZERO16, acc10 = ZERO16, acc11 = ZERO16;
#pragma unroll
      for (int kc = 0; kc < 8; ++kc) {
        int boff = ((kc * 2 + la5) * 128 + qcol * 64 + la31) << 4;
        bf16x8 b0 = *(const bf16x8*)(ybuf + boff);
        bf16x8 b1 = *(const bf16x8*)(ybuf + boff + (32 << 4));
        acc00 = __builtin_amdgcn_mfma_f32_32x32x16_bf16(Areg0[kc], b0, acc00, 0, 0, 0);
        acc01 = __builtin_amdgcn_mfma_f32_32x32x16_bf16(Areg0[kc], b1, acc01, 0, 0, 0);
        acc10 = __builtin_amdgcn_mfma_f32_32x32x16_bf16(Areg1[kc], b0, acc10, 0, 0, 0);
        acc11 = __builtin_amdgcn_mfma_f32_32x32x16_bf16(Areg1[kc], b1, acc11, 0, 0, 0);
      }
      // epilogue: u = yn - 2*dot; xn folded at end; clamp deferred
      float cm0 = BIGF, cm1 = BIGF;
#pragma unroll
      for (int r = 0; r < 16; ++r) {
        float u00 = fmaf(-2.f, acc00[r], ynr0);
        float u01 = fmaf(-2.f, acc01[r], ynr1);
        float u10 = fmaf(-2.f, acc10[r], ynr0);
        float u11 = fmaf(-2.f, acc11[r], ynr1);
        rmin[0][r] = fminf(rmin[0][r], fminf(u00, u01));
        rmin[1][r] = fminf(rmin[1][r], fminf(u10, u11));
        cm0 = fminf(cm0, fminf(u00 + xnr[0][r], u10 + xnr[1][r]));
        cm1 = fminf(cm1, fminf(u01 + xnr[0][r], u11 + xnr[1][r]));
      }
      cm0 = fminf(cm0, __shfl_xor(cm0, 32));   // merge la5 halves (rows)
      cm1 = fminf(cm1, __shfl_xor(cm1, 32));
      if (lane < 32) {
        atomicMin(&colmin_lds[jloc + la31],      __float_as_uint(fmaxf(cm0, 0.f)));
        atomicMin(&colmin_lds[jloc + 32 + la31], __float_as_uint(fmaxf(cm1, 0.f)));
      }
      __syncthreads();                  // drains prefetch + protects ybuf/colmin
      cur ^= 1;
    }

    // rowmin: reduce across 32 j-lanes, merge qcol halves via LDS atomics
#pragma unroll
    for (int fm = 0; fm < 2; ++fm)
#pragma unroll
      for (int r = 0; r < 16; ++r) {
        float v = rmin[fm][r];
        v = fminf(v, __shfl_xor(v, 1));
        v = fminf(v, __shfl_xor(v, 2));
        v = fminf(v, __shfl_xor(v, 4));
        v = fminf(v, __shfl_xor(v, 8));
        v = fminf(v, __shfl_xor(v, 16));
        if (la31 == 0) {
          int row = qrow * 64 + fm * 32 + (r & 3) + ((r >> 2) << 3) + (la5 << 2);
          atomicMin(&rowmin_lds[row], __float_as_uint(fmaxf(v + xnr[fm][r], 0.f)));
        }
      }
    __syncthreads();
    // merge to global (uint-ordered atomicMin; values nonneg)
    if (tid < 256) atomicMin(&rowming[i0 + tid], rowmin_lds[tid]);
    int jcnt = njt << 7;
    if (tid < jcnt) atomicMin(&colming[j0q + tid], colmin_lds[tid]);
  }

  // ---- completion protocol (ALL blocks) + fused final reduce ----
  __threadfence();
  __syncthreads();
  if (tid == 0) sh_done = atomicAdd((int*)(ws + OFF_CTR), 1);
  __syncthreads();
  if (sh_done == DGRID - 1) {
    __threadfence();
    unsigned* rminu = (unsigned*)(ws + OFF_RMIN);
    unsigned* cminu = (unsigned*)(ws + OFF_CMIN);
    float s = 0.f;
    for (int idx = tid; idx < BATCH * NPTS; idx += 512) {
      if (mask_at(mask, i32m, idx)) {
        // atomicOr(p,0): device-scope coherent read (value unchanged)
        unsigned rv = atomicOr(&rminu[idx], 0u);
        unsigned cv = atomicOr(&cminu[idx], 0u);
        s += __uint_as_float(rv) + __uint_as_float(cv);
      }
    }
    redbuf[tid] = s;
    __syncthreads();
    for (int st = 256; st > 0; st >>= 1) {
      if (tid < st) redbuf[tid] += redbuf[tid + st];
      __syncthreads();
    }
    if (tid == 0) out[0] = redbuf[0] * (1.f / BATCH);
  }
}

extern "C" void kernel_launch(void* const* d_in, const int* in_sizes, int n_in,
                              void* d_out, int out_size, void* d_ws, size_t ws_size,
                              hipStream_t stream) {
  const float* x = (const float*)d_in[0];
  const float* y = (const float*)d_in[1];
  const void* mask = d_in[2];
  float* out = (float*)d_out;
  char* ws = (char*)d_ws;

  chamfer_prep<<<2048, 256, 0, stream>>>(x, y, mask, ws);
  chamfer_dist<<<DGRID, 512, 0, stream>>>(ws, mask, out);
}